// Round 11
// baseline (908.188 us; speedup 1.0000x reference)
//
#include <hip/hip_runtime.h>

typedef unsigned short ushort_t;
typedef unsigned int   uint32;
typedef short s16x8 __attribute__((ext_vector_type(8)));
typedef float f32x4 __attribute__((ext_vector_type(4)));

#define HS    136    // h stride (272B rows)
#define KOF   0      // kE [68][136] = 9248 elems (score jt=4 overflow rows -> vT region, masked)
#define VOF   9248   // vT [128][72] = 9216 elems (cols 0..67 written; 64 = last real token)
#define SLOF  18464  // 10 per-wave slices x 2176 elems (q/P/O bounce + fsl)
#define EXOF  40224  // exchange: 5 mt x 2080 floats (16 rows x stride 130) = 41600 B
#define BIGN  61024  // big = 122048 B; + h 21760 B = 143808 B LDS -> 1 block/CU, 10 waves
#define EPS_  1e-5f
#define SCALE2_ 0.25503483f   // log2(e)/sqrt(32): scores pre-scaled for exp2 softmax

#define MFMA16(a,b,c) __builtin_amdgcn_mfma_f32_16x16x32_bf16((a),(b),(c),0,0,0)

__device__ __forceinline__ float bfu(ushort_t u) {
  union { uint32 i; float f; } c; c.i = ((uint32)u) << 16; return c.f;
}
__device__ __forceinline__ void bf2(uint32 u, float& a, float& b) {
  union { uint32 i; float f; } c0, c1;
  c0.i = u << 16; c1.i = u & 0xffff0000u; a = c0.f; b = c1.f;
}
__device__ __forceinline__ ushort_t f2bf(float f) {
  union { float f; uint32 i; } c; c.f = f;
  uint32 r = c.i + 0x7fffu + ((c.i >> 16) & 1u);
  return (ushort_t)(r >> 16);
}

// Statistical dtype sniff on the first 256 ushorts of x (fp32 vs bf16 buffer).
__device__ bool sniff_f32(const ushort_t* x) {
  int insane = 0, zeros = 0;
  for (int i = 0; i < 256; ++i) {
    ushort_t u = x[i];
    int e = (u >> 7) & 0xFF;
    if (u == 0) zeros++;
    else if (e == 0xFF || e < 0x60) insane++;
  }
  return (insane >= 16) || (zeros >= 64);
}

struct WPack {
  const void* src[23];
  unsigned    off[23];
  unsigned    n[23];
};

__global__ __launch_bounds__(256) void canon(WPack p, const ushort_t* x, ushort_t* dst,
                                             int* flagOut) {
  const bool f32 = sniff_f32(x);
  const int gid = blockIdx.x * blockDim.x + threadIdx.x;
  const int gsz = gridDim.x * blockDim.x;
  for (int a = 0; a < 23; ++a) {
    unsigned n = p.n[a];
    ushort_t* d = dst + p.off[a];
    if (f32) {
      const float* s = (const float*)p.src[a];
      for (unsigned i = gid; i < n; i += gsz) d[i] = f2bf(s[i]);
    } else {
      const ushort_t* s = (const ushort_t*)p.src[a];
      for (unsigned i = gid; i < n; i += gsz) d[i] = s[i];
    }
  }
  if (blockIdx.x == 0 && threadIdx.x == 0) *flagOut = f32 ? 1 : 0;
}

__global__ __launch_bounds__(640, 3)   // 10 waves, 1 block/CU (LDS 143.8 KB)
void vit_fused(const ushort_t* __restrict__ x,
               const ushort_t* __restrict__ patch_w,
               const ushort_t* __restrict__ patch_b,
               const ushort_t* __restrict__ cls_token,
               const ushort_t* __restrict__ pos_embed,
               const ushort_t* __restrict__ qkv_w,
               const ushort_t* __restrict__ qkv_b,
               const ushort_t* __restrict__ out_w,
               const ushort_t* __restrict__ out_b,
               const ushort_t* __restrict__ ln1_s,
               const ushort_t* __restrict__ ln1_b,
               const ushort_t* __restrict__ ln2_s,
               const ushort_t* __restrict__ ln2_b,
               const ushort_t* __restrict__ ff1_w,
               const ushort_t* __restrict__ ff1_b,
               const ushort_t* __restrict__ ff2_w,
               const ushort_t* __restrict__ ff2_b,
               const ushort_t* __restrict__ qr1_w,
               const ushort_t* __restrict__ qr1_b,
               const ushort_t* __restrict__ qr2_w,
               const ushort_t* __restrict__ qr2_b,
               const ushort_t* __restrict__ q_weights,
               const ushort_t* __restrict__ clf_w,
               const ushort_t* __restrict__ clf_b,
               const int* __restrict__ flag,
               void* __restrict__ out)
{
  __shared__ __align__(16) ushort_t h_s[80 * HS];   // 21760 B
  __shared__ __align__(16) ushort_t big[BIGN];      // 122048 B

  const int tid  = threadIdx.x;
  const int wid  = tid >> 6;          // 0..9
  const int lane = tid & 63;
  const int lr   = lane & 15;
  const int lq   = lane >> 4;
  const int b    = blockIdx.x;
  const bool f32m = (*flag != 0);
  const int mt   = wid >> 1;          // owned m-tile 0..4
  const int hg   = wid & 1;           // head-group: heads {2hg, 2hg+1}, ff-half hg
  const int m0   = mt * 16;

  ushort_t* bw  = big + SLOF + wid * 2176;            // private slice
  float*    exf = (float*)&big[EXOF] + mt * 2080;     // per-mt fp32 exchange [16][130]

  // ---------------- stage x + patch_w into big ----------------
  uint32* bx = (uint32*)big;
  if (f32m) {
    const float* xf = (const float*)x + (size_t)b * 3072;
    for (int i = tid; i < 1536; i += 640) {
      uint32 lo = f2bf(xf[2 * i]);
      uint32 hi = f2bf(xf[2 * i + 1]);
      bx[i] = lo | (hi << 16);
    }
  } else {
    const uint32* xb = (const uint32*)x + (size_t)b * 1536;
    for (int i = tid; i < 1536; i += 640) bx[i] = xb[i];
  }
  {
    const uint32* pw = (const uint32*)patch_w;
    for (int i = tid; i < 3072; i += 640) bx[1536 + i] = pw[i];
  }
  __syncthreads();

  // ---------------- patch embed (scalar, ~1% of MACs) ----------------
  #pragma unroll 1
  for (int idx = tid; idx < 8192; idx += 640) {
    int p = idx >> 7, d = idx & 127;
    int pi = p >> 3, pj = p & 7;
    float acc = 0.f;
    #pragma unroll
    for (int c = 0; c < 3; ++c) {
      #pragma unroll
      for (int py = 0; py < 4; ++py) {
        const uint32* xr = bx + ((c * 1024 + (pi * 4 + py) * 32 + pj * 4) >> 1);
        const uint32* wr = bx + 1536 + ((d * 48 + c * 16 + py * 4) >> 1);
        #pragma unroll
        for (int q2 = 0; q2 < 2; ++q2) {
          float xa, xb2, wa, wb;
          bf2(xr[q2], xa, xb2); bf2(wr[q2], wa, wb);
          acc += xa * wa + xb2 * wb;
        }
      }
    }
    acc += bfu(patch_b[d]) + bfu(pos_embed[(1 + p) * 128 + d]);
    h_s[(1 + p) * HS + d] = f2bf(acc);
  }
  if (tid < 128) h_s[tid] = f2bf(bfu(cls_token[tid]) + bfu(pos_embed[tid]));
  for (int i = tid; i < 15 * HS; i += 640) h_s[65 * HS + i] = 0;   // zero pad rows 65..79

  // ---------------- transformer layers ----------------
  #pragma unroll 1
  for (int il = 0; il < 4; ++il) {
    __syncthreads();   // B0: h stable; kE/vT/slices free

    const ushort_t* Wqkv = qkv_w + (size_t)il * 384 * 128;
    const ushort_t* Bqkv = qkv_b + il * 384;
    const ushort_t* Wo   = out_w + (size_t)il * 128 * 128;

    // ---- phase 1: k_all / vT_all — 8 units/wave
    #pragma unroll 2
    for (int u = wid * 8; u < wid * 8 + 8; ++u) {
      int ty = u & 1, r = u >> 1;
      int kmt = r >> 3, nt = r & 7;
      int km0 = kmt * 16;
      int rb = (ty ? 256 : 128) + nt * 16;
      float bv = bfu(Bqkv[rb + lr]);
      f32x4 acc = {bv, bv, bv, bv};
      #pragma unroll
      for (int kc = 0; kc < 4; ++kc) {
        s16x8 a  = *(const s16x8*)&h_s[(km0 + lr) * HS + kc * 32 + lq * 8];
        s16x8 bb = *(const s16x8*)&Wqkv[(rb + lr) * 128 + kc * 32 + lq * 8];
        acc = MFMA16(a, bb, acc);
      }
      if (!ty) {   // k[token][dim], stride 136, rows < 68
        #pragma unroll
        for (int i = 0; i < 4; ++i) {
          int row = km0 + lq * 4 + i;
          if (row < 68) big[KOF + row * 136 + nt * 16 + lr] = f2bf(acc[i]);
        }
      } else {     // vT[dim][token], stride 72, tokens < 68
        int tk = km0 + lq * 4;
        if (tk < 68) {
          uint32 w0 = (uint32)f2bf(acc[0]) | ((uint32)f2bf(acc[1]) << 16);
          uint32 w1 = (uint32)f2bf(acc[2]) | ((uint32)f2bf(acc[3]) << 16);
          uint32* dst = (uint32*)&big[VOF + (nt * 16 + lr) * 72 + tk];
          dst[0] = w0; dst[1] = w1;
        }
      }
    }
    __syncthreads();   // B1: kE / vT ready

    // ---- attention: 2 heads per wave; partial out-proj in opA ----
    f32x4 opA[8];
    #pragma unroll
    for (int nt = 0; nt < 8; ++nt) {
      float bv = (hg == 0) ? bfu(out_b[il * 128 + nt * 16 + lr]) : 0.f;
      opA[nt] = (f32x4){bv, bv, bv, bv};
    }
    {
      s16x8 ha[4];
      #pragma unroll
      for (int kc = 0; kc < 4; ++kc)
        ha[kc] = *(const s16x8*)&h_s[(m0 + lr) * HS + kc * 32 + lq * 8];
      #pragma unroll 1
      for (int hh = 0; hh < 2; ++hh) {
        int ih = hg * 2 + hh;
        // q projection (pre-scaled)
        #pragma unroll
        for (int n2 = 0; n2 < 2; ++n2) {
          int rb = ih * 32 + n2 * 16;
          float bv = bfu(Bqkv[rb + lr]);
          f32x4 acc = {bv, bv, bv, bv};
          #pragma unroll
          for (int kc = 0; kc < 4; ++kc) {
            s16x8 bb = *(const s16x8*)&Wqkv[(rb + lr) * 128 + kc * 32 + lq * 8];
            acc = MFMA16(ha[kc], bb, acc);
          }
          #pragma unroll
          for (int i = 0; i < 4; ++i)
            bw[(lq * 4 + i) * 40 + n2 * 16 + lr] = f2bf(acc[i] * SCALE2_);
        }
        s16x8 aq = *(const s16x8*)&bw[lr * 40 + lq * 8];
        // scores (jt=4 rows 65..79 read finite garbage: masked by assignment)
        f32x4 S[5];
        #pragma unroll
        for (int jt = 0; jt < 5; ++jt) {
          s16x8 bb = *(const s16x8*)&big[KOF + (jt * 16 + lr) * 136 + ih * 32 + lq * 8];
          f32x4 z = {0.f, 0.f, 0.f, 0.f};
          S[jt] = MFMA16(aq, bb, z);
        }
        float mx[4] = {-1e30f, -1e30f, -1e30f, -1e30f};
        #pragma unroll
        for (int jt = 0; jt < 5; ++jt)
          #pragma unroll
          for (int i = 0; i < 4; ++i) {
            float sv = S[jt][i];
            if (jt == 4 && lr > 0) sv = -1e30f;
            S[jt][i] = sv;
            mx[i] = fmaxf(mx[i], sv);
          }
        #pragma unroll
        for (int off = 1; off < 16; off <<= 1)
          #pragma unroll
          for (int i = 0; i < 4; ++i) mx[i] = fmaxf(mx[i], __shfl_xor(mx[i], off));
        float sm[4] = {0.f, 0.f, 0.f, 0.f};
        #pragma unroll
        for (int jt = 0; jt < 5; ++jt)
          #pragma unroll
          for (int i = 0; i < 4; ++i) {
            float pv = exp2f(S[jt][i] - mx[i]);
            S[jt][i] = pv; sm[i] += pv;
          }
        #pragma unroll
        for (int off = 1; off < 16; off <<= 1)
          #pragma unroll
          for (int i = 0; i < 4; ++i) sm[i] += __shfl_xor(sm[i], off);
        float inv[4];
        #pragma unroll
        for (int i = 0; i < 4; ++i) inv[i] = 1.f / sm[i];
        #pragma unroll
        for (int i = 0; i < 4; ++i)
          #pragma unroll
          for (int jt = 0; jt < 4; ++jt)
            bw[(lq * 4 + i) * 72 + jt * 16 + lr] = f2bf(S[jt][i] * inv[i]);
        // PV tokens 0..63 (MFMA) + token 64 (VALU)
        f32x4 ov[2];
        #pragma unroll
        for (int n2 = 0; n2 < 2; ++n2) {
          f32x4 acc = {0.f, 0.f, 0.f, 0.f};
          #pragma unroll
          for (int kc = 0; kc < 2; ++kc) {
            s16x8 a  = *(const s16x8*)&bw[lr * 72 + kc * 32 + lq * 8];
            s16x8 bb = *(const s16x8*)&big[VOF + (ih * 32 + n2 * 16 + lr) * 72 + kc * 32 + lq * 8];
            acc = MFMA16(a, bb, acc);
          }
          float v64 = bfu(big[VOF + (ih * 32 + n2 * 16 + lr) * 72 + 64]);
          #pragma unroll
          for (int i = 0; i < 4; ++i) {
            float p64 = __shfl(S[4][i], lane & 48) * inv[i];
            acc[i] += p64 * v64;
          }
          ov[n2] = acc;
        }
        // O bounce -> A-frag -> partial out-proj
        #pragma unroll
        for (int n2 = 0; n2 < 2; ++n2)
          #pragma unroll
          for (int i = 0; i < 4; ++i)
            bw[(lq * 4 + i) * 40 + n2 * 16 + lr] = f2bf(ov[n2][i]);
        s16x8 ao = *(const s16x8*)&bw[lr * 40 + lq * 8];
        #pragma unroll
        for (int nt = 0; nt < 8; ++nt) {
          s16x8 bb = *(const s16x8*)&Wo[(nt * 16 + lr) * 128 + ih * 32 + lq * 8];
          opA[nt] = MFMA16(ao, bb, opA[nt]);
        }
      } // 2 heads
    }
    // hg=1: publish fp32 partial (stride 130 -> 2-way banks, free)
    if (hg == 1) {
      #pragma unroll
      for (int nt = 0; nt < 8; ++nt)
        #pragma unroll
        for (int i = 0; i < 4; ++i)
          exf[(lq * 4 + i) * 130 + nt * 16 + lr] = opA[nt][i];
    }
    __syncthreads();   // B2: exchange ready
    if (hg == 0) {     // reduce + residual + LN1 + write h (own mt rows)
      float sv[4] = {0, 0, 0, 0}, ssv[4] = {0, 0, 0, 0};
      #pragma unroll
      for (int nt = 0; nt < 8; ++nt)
        #pragma unroll
        for (int i = 0; i < 4; ++i) {
          float r = opA[nt][i] + exf[(lq * 4 + i) * 130 + nt * 16 + lr]
                  + bfu(h_s[(m0 + lq * 4 + i) * HS + nt * 16 + lr]);
          opA[nt][i] = r; sv[i] += r; ssv[i] += r * r;
        }
      #pragma unroll
      for (int off = 1; off < 16; off <<= 1)
        #pragma unroll
        for (int i = 0; i < 4; ++i) {
          sv[i]  += __shfl_xor(sv[i], off);
          ssv[i] += __shfl_xor(ssv[i], off);
        }
      #pragma unroll
      for (int nt = 0; nt < 8; ++nt) {
        float g  = bfu(ln1_s[il * 128 + nt * 16 + lr]);
        float be = bfu(ln1_b[il * 128 + nt * 16 + lr]);
        #pragma unroll
        for (int i = 0; i < 4; ++i) {
          float mean = sv[i] * (1.f / 128.f);
          float iv   = rsqrtf(fmaxf(ssv[i] * (1.f / 128.f) - mean * mean, 0.f) + EPS_);
          h_s[(m0 + lq * 4 + i) * HS + nt * 16 + lr] =
              f2bf((opA[nt][i] - mean) * iv * g + be);
        }
      }
    }
    __syncthreads();   // B3: h(LN1) ready

    // ---- FF: ff1 own half -> own fsl; ff2 own K-half -> partial acc2 ----
    {
      const ushort_t* W1 = ff1_w + (size_t)il * 256 * 128;
      const ushort_t* W2 = ff2_w + (size_t)il * 128 * 256;
      s16x8 hf[4];
      #pragma unroll
      for (int kc = 0; kc < 4; ++kc)
        hf[kc] = *(const s16x8*)&h_s[(m0 + lr) * HS + kc * 32 + lq * 8];
      f32x4 acc2[8];
      #pragma unroll
      for (int nt = 0; nt < 8; ++nt) {
        float bv = (hg == 0) ? bfu(ff2_b[il * 128 + nt * 16 + lr]) : 0.f;
        acc2[nt] = (f32x4){bv, bv, bv, bv};
      }
      #pragma unroll 2
      for (int n8 = 0; n8 < 8; ++n8) {
        int ng = hg * 8 + n8;
        float bv = bfu(ff1_b[il * 256 + ng * 16 + lr]);
        f32x4 acc = {bv, bv, bv, bv};
        #pragma unroll
        for (int kc = 0; kc < 4; ++kc) {
          s16x8 bb = *(const s16x8*)&W1[(ng * 16 + lr) * 128 + kc * 32 + lq * 8];
          acc = MFMA16(hf[kc], bb, acc);
        }
        #pragma unroll
        for (int i = 0; i < 4; ++i)
          bw[(lq * 4 + i) * 136 + n8 * 16 + lr] = f2bf(fmaxf(acc[i], 0.f));
      }
      #pragma unroll
      for (int kc = 0; kc < 4; ++kc) {
        s16x8 a2 = *(const s16x8*)&bw[lr * 136 + kc * 32 + lq * 8];
        #pragma unroll
        for (int nt = 0; nt < 8; ++nt) {
          s16x8 bb = *(const s16x8*)&W2[(nt * 16 + lr) * 256 + hg * 128 + kc * 32 + lq * 8];
          acc2[nt] = MFMA16(a2, bb, acc2[nt]);
        }
      }
      if (hg == 1) {
        #pragma unroll
        for (int nt = 0; nt < 8; ++nt)
          #pragma unroll
          for (int i = 0; i < 4; ++i)
            exf[(lq * 4 + i) * 130 + nt * 16 + lr] = acc2[nt][i];
      }
      __syncthreads();   // B4: ff2 exchange ready
      if (hg == 0) {     // reduce + residual + LN2 + write h
        float sv[4] = {0, 0, 0, 0}, ssv[4] = {0, 0, 0, 0};
        #pragma unroll
        for (int nt = 0; nt < 8; ++nt)
          #pragma unroll
          for (int i = 0; i < 4; ++i) {
            float r = acc2[nt][i] + exf[(lq * 4 + i) * 130 + nt * 16 + lr]
                    + bfu(h_s[(m0 + lq * 4 + i) * HS + nt * 16 + lr]);
            acc2[nt][i] = r; sv[i] += r; ssv[i] += r * r;
          }
        #pragma unroll
        for (int off = 1; off < 16; off <<= 1)
          #pragma unroll
          for (int i = 0; i < 4; ++i) {
            sv[i]  += __shfl_xor(sv[i], off);
            ssv[i] += __shfl_xor(ssv[i], off);
          }
        #pragma unroll
        for (int nt = 0; nt < 8; ++nt) {
          float g  = bfu(ln2_s[il * 128 + nt * 16 + lr]);
          float be = bfu(ln2_b[il * 128 + nt * 16 + lr]);
          #pragma unroll
          for (int i = 0; i < 4; ++i) {
            float mean = sv[i] * (1.f / 128.f);
            float iv   = rsqrtf(fmaxf(ssv[i] * (1.f / 128.f) - mean * mean, 0.f) + EPS_);
            h_s[(m0 + lq * 4 + i) * HS + nt * 16 + lr] =
                f2bf((acc2[nt][i] - mean) * iv * g + be);
          }
        }
      }
    }
  } // layers

  // ---------------- head (tiny scalar) ----------------
  __syncthreads();
  float* scr = (float*)big;
  {
    int j = tid & 31;
    const uint32* hrow0 = (const uint32*)h_s;
    const uint32* w = (const uint32*)qr1_w + j * 64;
    float acc = 0.f;
    #pragma unroll 4
    for (int k2 = 0; k2 < 64; ++k2) {
      float ha, hb, wa, wb;
      bf2(hrow0[k2], ha, hb); bf2(w[k2], wa, wb);
      acc += ha * wa + hb * wb;
    }
    float u = fmaxf(acc + bfu(qr1_b[j]), 0.f);
    if (tid < 32) scr[tid] = u;
  }
  __syncthreads();
  if (tid < 10) {
    float qo[4]; float cp = 1.f;
    #pragma unroll
    for (int j2 = 0; j2 < 4; ++j2) {
      float acc = 0.f;
      #pragma unroll
      for (int k = 0; k < 32; ++k) acc += scr[k] * bfu(qr2_w[j2 * 32 + k]);
      float qin = tanhf(acc + bfu(qr2_b[j2]));
      cp *= cosf(qin) * cosf(bfu(q_weights[j2]));
      qo[j2] = cp;
    }
    const uint32* hrow0 = (const uint32*)h_s;
    const uint32* cw = (const uint32*)clf_w + tid * 66;   // clf row stride 132 elems
    float acc = 0.f;
    #pragma unroll 4
    for (int k2 = 0; k2 < 64; ++k2) {
      float ha, hb, wa, wb;
      bf2(hrow0[k2], ha, hb); bf2(cw[k2], wa, wb);
      acc += ha * wa + hb * wb;
    }
    #pragma unroll
    for (int d = 0; d < 4; ++d) acc += qo[d] * bfu(clf_w[tid * 132 + 128 + d]);
    acc += bfu(clf_b[tid]);
    if (f32m) ((float*)out)[b * 10 + tid] = acc;
    else      ((ushort_t*)out)[b * 10 + tid] = f2bf(acc);
  }
}

extern "C" void kernel_launch(void* const* d_in, const int* in_sizes, int n_in,
                              void* d_out, int out_size, void* d_ws, size_t ws_size,
                              hipStream_t stream) {
  WPack p;
  unsigned cur = 0;
  for (int i = 0; i < 23; ++i) {
    p.src[i] = d_in[i + 1];
    p.off[i] = cur;
    p.n[i]   = (unsigned)in_sizes[i + 1];
    cur += (p.n[i] + 7u) & ~7u;
  }
  ushort_t* wsb = (ushort_t*)d_ws;
  unsigned flag_off = (cur * 2 + 3u) & ~3u;          // byte offset, 4B aligned
  int* flagp = (int*)((char*)d_ws + flag_off);
  const ushort_t* x = (const ushort_t*)d_in[0];

  canon<<<dim3(128), dim3(256), 0, stream>>>(p, x, wsb, flagp);

  int B = out_size / 10;
  vit_fused<<<dim3(B), dim3(640), 0, stream>>>(
      x,
      wsb + p.off[0],  wsb + p.off[1],  wsb + p.off[2],  wsb + p.off[3],
      wsb + p.off[4],  wsb + p.off[5],  wsb + p.off[6],  wsb + p.off[7],
      wsb + p.off[8],  wsb + p.off[9],  wsb + p.off[10], wsb + p.off[11],
      wsb + p.off[12], wsb + p.off[13], wsb + p.off[14], wsb + p.off[15],
      wsb + p.off[16], wsb + p.off[17], wsb + p.off[18], wsb + p.off[19],
      wsb + p.off[20], wsb + p.off[21], wsb + p.off[22],
      flagp, d_out);
}

// Round 12
// 724.317 us; speedup vs baseline: 1.2539x; 1.2539x over previous
//
#include <hip/hip_runtime.h>

typedef unsigned short ushort_t;
typedef unsigned int   uint32;
typedef short s16x8 __attribute__((ext_vector_type(8)));
typedef float f32x4 __attribute__((ext_vector_type(4)));

#define EPS_  1e-5f
#define SCALE2_ 0.25503483f   // log2(e)/sqrt(32)
#define MFMA16(a,b,c) __builtin_amdgcn_mfma_f32_16x16x32_bf16((a),(b),(c),0,0,0)

__device__ __forceinline__ float bfu(ushort_t u) {
  union { uint32 i; float f; } c; c.i = ((uint32)u) << 16; return c.f;
}
__device__ __forceinline__ void bf2(uint32 u, float& a, float& b) {
  union { uint32 i; float f; } c0, c1;
  c0.i = u << 16; c1.i = u & 0xffff0000u; a = c0.f; b = c1.f;
}
__device__ __forceinline__ ushort_t f2bf(float f) {
  union { float f; uint32 i; } c; c.f = f;
  uint32 r = c.i + 0x7fffu + ((c.i >> 16) & 1u);
  return (ushort_t)(r >> 16);
}

__device__ bool sniff_f32(const ushort_t* x) {
  int insane = 0, zeros = 0;
  for (int i = 0; i < 256; ++i) {
    ushort_t u = x[i];
    int e = (u >> 7) & 0xFF;
    if (u == 0) zeros++;
    else if (e == 0xFF || e < 0x60) insane++;
  }
  return (insane >= 16) || (zeros >= 64);
}

struct WPack {
  const void* src[23];
  unsigned    off[23];
  unsigned    n[23];
};

__global__ __launch_bounds__(256) void canon(WPack p, const ushort_t* x, ushort_t* dst,
                                             int* flagOut) {
  const bool f32 = sniff_f32(x);
  const int gid = blockIdx.x * blockDim.x + threadIdx.x;
  const int gsz = gridDim.x * blockDim.x;
  for (int a = 0; a < 23; ++a) {
    unsigned n = p.n[a];
    ushort_t* d = dst + p.off[a];
    if (f32) {
      const float* s = (const float*)p.src[a];
      for (unsigned i = gid; i < n; i += gsz) d[i] = f2bf(s[i]);
    } else {
      const ushort_t* s = (const ushort_t*)p.src[a];
      for (unsigned i = gid; i < n; i += gsz) d[i] = s[i];
    }
  }
  if (blockIdx.x == 0 && threadIdx.x == 0) *flagOut = f32 ? 1 : 0;
}

// ================= pipeline kernels =================

// patch embed + cls + pos -> hbuf [B*65][128]
__global__ __launch_bounds__(256)
void k_patch(const ushort_t* __restrict__ x, const ushort_t* __restrict__ patch_w,
             const ushort_t* __restrict__ patch_b, const ushort_t* __restrict__ cls_token,
             const ushort_t* __restrict__ pos_embed, const int* __restrict__ flag,
             ushort_t* __restrict__ hbuf) {
  __shared__ uint32 bx[4608];
  const int tid = threadIdx.x, b = blockIdx.x;
  const bool f32m = (*flag != 0);
  if (f32m) {
    const float* xf = (const float*)x + (size_t)b * 3072;
    for (int i = tid; i < 1536; i += 256) {
      uint32 lo = f2bf(xf[2 * i]);
      uint32 hi = f2bf(xf[2 * i + 1]);
      bx[i] = lo | (hi << 16);
    }
  } else {
    const uint32* xb = (const uint32*)x + (size_t)b * 1536;
    for (int i = tid; i < 1536; i += 256) bx[i] = xb[i];
  }
  {
    const uint32* pw = (const uint32*)patch_w;
    for (int i = tid; i < 3072; i += 256) bx[1536 + i] = pw[i];
  }
  __syncthreads();
  #pragma unroll 1
  for (int it = 0; it < 32; ++it) {
    int idx = tid + 256 * it;
    int p = idx >> 7, d = idx & 127;
    int pi = p >> 3, pj = p & 7;
    float acc = 0.f;
    #pragma unroll
    for (int c = 0; c < 3; ++c)
      #pragma unroll
      for (int py = 0; py < 4; ++py) {
        const uint32* xr = bx + ((c * 1024 + (pi * 4 + py) * 32 + pj * 4) >> 1);
        const uint32* wr = bx + 1536 + ((d * 48 + c * 16 + py * 4) >> 1);
        #pragma unroll
        for (int q2 = 0; q2 < 2; ++q2) {
          float xa, xb2, wa, wb;
          bf2(xr[q2], xa, xb2); bf2(wr[q2], wa, wb);
          acc += xa * wa + xb2 * wb;
        }
      }
    acc += bfu(patch_b[d]) + bfu(pos_embed[(1 + p) * 128 + d]);
    hbuf[((size_t)b * 65 + 1 + p) * 128 + d] = f2bf(acc);
  }
  if (tid < 128)
    hbuf[(size_t)b * 65 * 128 + tid] = f2bf(bfu(cls_token[tid]) + bfu(pos_embed[tid]));
}

// qkv GEMM: hbuf[M=65B][128] @ W[384][128]^T -> scatter to q/k/vT bufs (per b,h)
__global__ __launch_bounds__(256)
void k_qkv(const ushort_t* __restrict__ hbuf, const ushort_t* __restrict__ W,
           const ushort_t* __restrict__ bias, ushort_t* __restrict__ qb,
           ushort_t* __restrict__ kb, ushort_t* __restrict__ vtb) {
  __shared__ __align__(16) ushort_t Bs[64 * 136];
  const int tid = threadIdx.x, wid = tid >> 6, lane = tid & 63;
  const int lr = lane & 15, lq = lane >> 4;
  const int bm = blockIdx.x, nc = blockIdx.y;   // M-tile, 64-col chunk of 384
  {
    const uint32* Wd = (const uint32*)W;
    uint32* Bd = (uint32*)Bs;
    for (int i = tid; i < 4096; i += 256) {
      int row = i >> 6, cw = i & 63;
      Bd[row * 68 + cw] = Wd[(nc * 64 + row) * 64 + cw];
    }
  }
  __syncthreads();
  const int r0 = bm * 64 + wid * 16;
  s16x8 a[4];
  #pragma unroll
  for (int kc = 0; kc < 4; ++kc)
    a[kc] = *(const s16x8*)&hbuf[(size_t)(r0 + lr) * 128 + kc * 32 + lq * 8];
  #pragma unroll
  for (int nt = 0; nt < 4; ++nt) {
    int c0 = nc * 64 + nt * 16;
    float bv = bfu(bias[c0 + lr]);
    f32x4 acc = {bv, bv, bv, bv};
    #pragma unroll
    for (int kc = 0; kc < 4; ++kc) {
      s16x8 bb = *(const s16x8*)&Bs[(nt * 16 + lr) * 136 + kc * 32 + lq * 8];
      acc = MFMA16(a[kc], bb, acc);
    }
    int c = c0 + lr;
    #pragma unroll
    for (int i = 0; i < 4; ++i) {
      int r = r0 + lq * 4 + i;
      int b = r / 65, t = r - b * 65;
      if (c0 < 128) {          // q (pre-scaled)
        int h = c >> 5, d = c & 31;
        qb[((size_t)(b * 4 + h) * 80 + t) * 32 + d] = f2bf(acc[i] * SCALE2_);
      } else if (c0 < 256) {   // k
        int c2 = c - 128;
        kb[((size_t)(b * 4 + (c2 >> 5)) * 80 + t) * 32 + (c2 & 31)] = f2bf(acc[i]);
      } else {                 // v transposed
        int c2 = c - 256;
        vtb[((size_t)(b * 4 + (c2 >> 5)) * 32 + (c2 & 31)) * 80 + t] = f2bf(acc[i]);
      }
    }
  }
}

// attention: one wave per (b,h). q/k pre-scaled; writes obuf token-major.
__global__ __launch_bounds__(64)
void k_attn(const ushort_t* __restrict__ qb, const ushort_t* __restrict__ kb,
            const ushort_t* __restrict__ vtb, ushort_t* __restrict__ obuf) {
  __shared__ __align__(16) ushort_t ks[80 * 40];   // k rows (65..79 finite poison, masked)
  __shared__ __align__(16) ushort_t vs[32 * 96];   // vT dims x tokens
  __shared__ __align__(16) ushort_t ps[16 * 96];   // P slice
  const int lane = threadIdx.x;
  const int lr = lane & 15, lq = lane >> 4;
  const int bh = blockIdx.x;
  {
    const uint32* kd = (const uint32*)(kb + (size_t)bh * 2560);
    uint32* kls = (uint32*)ks;
    #pragma unroll
    for (int it = 0; it < 20; ++it) {
      int u = it * 64 + lane;
      kls[(u >> 4) * 20 + (u & 15)] = kd[u];
    }
    const uint32* vd = (const uint32*)(vtb + (size_t)bh * 2560);
    uint32* vls = (uint32*)vs;
    #pragma unroll
    for (int it = 0; it < 20; ++it) {
      int u = it * 64 + lane;
      vls[(u / 40) * 48 + (u % 40)] = vd[u];
    }
    for (int u = lane; u < 512; u += 64)            // zero vT pad cols 80..95
      vs[(u >> 4) * 96 + 80 + (u & 15)] = 0;
  }
  __syncthreads();
  const int b = bh >> 2, h = bh & 3;
  #pragma unroll 1
  for (int mt = 0; mt < 5; ++mt) {
    s16x8 aq = *(const s16x8*)&qb[((size_t)bh * 80 + mt * 16 + lr) * 32 + lq * 8];
    f32x4 S[5];
    #pragma unroll
    for (int jt = 0; jt < 5; ++jt) {
      s16x8 bb = *(const s16x8*)&ks[(jt * 16 + lr) * 40 + lq * 8];
      f32x4 z = {0.f, 0.f, 0.f, 0.f};
      S[jt] = MFMA16(aq, bb, z);
    }
    float mx[4] = {-1e30f, -1e30f, -1e30f, -1e30f};
    #pragma unroll
    for (int jt = 0; jt < 5; ++jt)
      #pragma unroll
      for (int i = 0; i < 4; ++i) {
        float sv = S[jt][i];
        if (jt == 4 && lr > 0) sv = -1e30f;   // mask keys 65..79
        S[jt][i] = sv;
        mx[i] = fmaxf(mx[i], sv);
      }
    #pragma unroll
    for (int off = 1; off < 16; off <<= 1)
      #pragma unroll
      for (int i = 0; i < 4; ++i) mx[i] = fmaxf(mx[i], __shfl_xor(mx[i], off));
    float sm[4] = {0.f, 0.f, 0.f, 0.f};
    #pragma unroll
    for (int jt = 0; jt < 5; ++jt)
      #pragma unroll
      for (int i = 0; i < 4; ++i) {
        float pv = exp2f(S[jt][i] - mx[i]);
        S[jt][i] = pv; sm[i] += pv;
      }
    #pragma unroll
    for (int off = 1; off < 16; off <<= 1)
      #pragma unroll
      for (int i = 0; i < 4; ++i) sm[i] += __shfl_xor(sm[i], off);
    float inv[4];
    #pragma unroll
    for (int i = 0; i < 4; ++i) inv[i] = 1.f / sm[i];
    #pragma unroll
    for (int i = 0; i < 4; ++i) {
      #pragma unroll
      for (int jt = 0; jt < 5; ++jt)
        ps[(lq * 4 + i) * 96 + jt * 16 + lr] = f2bf(S[jt][i] * inv[i]);
      ps[(lq * 4 + i) * 96 + 80 + lr] = 0;
    }
    #pragma unroll
    for (int n2 = 0; n2 < 2; ++n2) {
      f32x4 acc = {0.f, 0.f, 0.f, 0.f};
      #pragma unroll
      for (int kc = 0; kc < 3; ++kc) {
        s16x8 a  = *(const s16x8*)&ps[lr * 96 + kc * 32 + lq * 8];
        s16x8 bb = *(const s16x8*)&vs[(n2 * 16 + lr) * 96 + kc * 32 + lq * 8];
        acc = MFMA16(a, bb, acc);
      }
      #pragma unroll
      for (int i = 0; i < 4; ++i) {
        int t = mt * 16 + lq * 4 + i;
        if (t < 65)
          obuf[((size_t)b * 65 + t) * 128 + h * 32 + n2 * 16 + lr] = f2bf(acc[i]);
      }
    }
  }
}

// outproj + residual + LN1: obuf @ Wo^T (+out_b) + hbuf -> LN -> hbuf
__global__ __launch_bounds__(256)
void k_out_ln(const ushort_t* __restrict__ obuf, const ushort_t* __restrict__ Wo,
              const ushort_t* __restrict__ ob, const ushort_t* __restrict__ g,
              const ushort_t* __restrict__ be, ushort_t* __restrict__ hbuf) {
  __shared__ __align__(16) ushort_t Bs[128 * 136];
  const int tid = threadIdx.x, wid = tid >> 6, lane = tid & 63;
  const int lr = lane & 15, lq = lane >> 4;
  const int bm = blockIdx.x;
  {
    const uint32* Wd = (const uint32*)Wo;
    uint32* Bd = (uint32*)Bs;
    for (int i = tid; i < 8192; i += 256)
      Bd[(i >> 6) * 68 + (i & 63)] = Wd[i];
  }
  __syncthreads();
  const int r0 = bm * 64 + wid * 16;
  s16x8 a[4];
  #pragma unroll
  for (int kc = 0; kc < 4; ++kc)
    a[kc] = *(const s16x8*)&obuf[(size_t)(r0 + lr) * 128 + kc * 32 + lq * 8];
  float xr[8][4];
  float sv[4] = {0, 0, 0, 0}, ssv[4] = {0, 0, 0, 0};
  #pragma unroll
  for (int nt = 0; nt < 8; ++nt) {
    float bv = bfu(ob[nt * 16 + lr]);
    f32x4 acc = {bv, bv, bv, bv};
    #pragma unroll
    for (int kc = 0; kc < 4; ++kc) {
      s16x8 bb = *(const s16x8*)&Bs[(nt * 16 + lr) * 136 + kc * 32 + lq * 8];
      acc = MFMA16(a[kc], bb, acc);
    }
    #pragma unroll
    for (int i = 0; i < 4; ++i) {
      float r = acc[i] + bfu(hbuf[(size_t)(r0 + lq * 4 + i) * 128 + nt * 16 + lr]);
      xr[nt][i] = r; sv[i] += r; ssv[i] += r * r;
    }
  }
  #pragma unroll
  for (int off = 1; off < 16; off <<= 1)
    #pragma unroll
    for (int i = 0; i < 4; ++i) {
      sv[i]  += __shfl_xor(sv[i], off);
      ssv[i] += __shfl_xor(ssv[i], off);
    }
  #pragma unroll
  for (int nt = 0; nt < 8; ++nt) {
    float gg = bfu(g[nt * 16 + lr]);
    float bb = bfu(be[nt * 16 + lr]);
    #pragma unroll
    for (int i = 0; i < 4; ++i) {
      float mean = sv[i] * (1.f / 128.f);
      float iv = rsqrtf(fmaxf(ssv[i] * (1.f / 128.f) - mean * mean, 0.f) + EPS_);
      hbuf[(size_t)(r0 + lq * 4 + i) * 128 + nt * 16 + lr] =
          f2bf((xr[nt][i] - mean) * iv * gg + bb);
    }
  }
}

// ff1: hbuf @ W1^T (+b) relu -> fbuf[M][256]
__global__ __launch_bounds__(256)
void k_ff1(const ushort_t* __restrict__ hbuf, const ushort_t* __restrict__ W1,
           const ushort_t* __restrict__ b1, ushort_t* __restrict__ fbuf) {
  __shared__ __align__(16) ushort_t Bs[64 * 136];
  const int tid = threadIdx.x, wid = tid >> 6, lane = tid & 63;
  const int lr = lane & 15, lq = lane >> 4;
  const int bm = blockIdx.x, nc = blockIdx.y;
  {
    const uint32* Wd = (const uint32*)W1;
    uint32* Bd = (uint32*)Bs;
    for (int i = tid; i < 4096; i += 256) {
      int row = i >> 6, cw = i & 63;
      Bd[row * 68 + cw] = Wd[(nc * 64 + row) * 64 + cw];
    }
  }
  __syncthreads();
  const int r0 = bm * 64 + wid * 16;
  s16x8 a[4];
  #pragma unroll
  for (int kc = 0; kc < 4; ++kc)
    a[kc] = *(const s16x8*)&hbuf[(size_t)(r0 + lr) * 128 + kc * 32 + lq * 8];
  #pragma unroll
  for (int nt = 0; nt < 4; ++nt) {
    int c0 = nc * 64 + nt * 16;
    float bv = bfu(b1[c0 + lr]);
    f32x4 acc = {bv, bv, bv, bv};
    #pragma unroll
    for (int kc = 0; kc < 4; ++kc) {
      s16x8 bb = *(const s16x8*)&Bs[(nt * 16 + lr) * 136 + kc * 32 + lq * 8];
      acc = MFMA16(a[kc], bb, acc);
    }
    #pragma unroll
    for (int i = 0; i < 4; ++i)
      fbuf[(size_t)(r0 + lq * 4 + i) * 256 + c0 + lr] = f2bf(fmaxf(acc[i], 0.f));
  }
}

// ff2 + residual + LN2: fbuf @ W2^T (+b) + hbuf -> LN -> hbuf
__global__ __launch_bounds__(256)
void k_ff2_ln(const ushort_t* __restrict__ fbuf, const ushort_t* __restrict__ W2,
              const ushort_t* __restrict__ b2, const ushort_t* __restrict__ g,
              const ushort_t* __restrict__ be, ushort_t* __restrict__ hbuf) {
  __shared__ __align__(16) ushort_t Bs[128 * 136];
  const int tid = threadIdx.x, wid = tid >> 6, lane = tid & 63;
  const int lr = lane & 15, lq = lane >> 4;
  const int bm = blockIdx.x;
  const int r0 = bm * 64 + wid * 16;
  f32x4 acc2[8];
  #pragma unroll
  for (int nt = 0; nt < 8; ++nt) {
    float bv = bfu(b2[nt * 16 + lr]);
    acc2[nt] = (f32x4){bv, bv, bv, bv};
  }
  #pragma unroll 1
  for (int half = 0; half < 2; ++half) {
    {
      const uint32* Wd = (const uint32*)W2;
      uint32* Bd = (uint32*)Bs;
      for (int i = tid; i < 8192; i += 256) {
        int row = i >> 6, cw = i & 63;
        Bd[row * 68 + cw] = Wd[row * 128 + half * 64 + cw];
      }
    }
    __syncthreads();
    s16x8 a[4];
    #pragma unroll
    for (int kc = 0; kc < 4; ++kc)
      a[kc] = *(const s16x8*)&fbuf[(size_t)(r0 + lr) * 256 + half * 128 + kc * 32 + lq * 8];
    #pragma unroll
    for (int nt = 0; nt < 8; ++nt)
      #pragma unroll
      for (int kc = 0; kc < 4; ++kc) {
        s16x8 bb = *(const s16x8*)&Bs[(nt * 16 + lr) * 136 + kc * 32 + lq * 8];
        acc2[nt] = MFMA16(a[kc], bb, acc2[nt]);
      }
    __syncthreads();
  }
  float sv[4] = {0, 0, 0, 0}, ssv[4] = {0, 0, 0, 0};
  #pragma unroll
  for (int nt = 0; nt < 8; ++nt)
    #pragma unroll
    for (int i = 0; i < 4; ++i) {
      float r = acc2[nt][i] + bfu(hbuf[(size_t)(r0 + lq * 4 + i) * 128 + nt * 16 + lr]);
      acc2[nt][i] = r; sv[i] += r; ssv[i] += r * r;
    }
  #pragma unroll
  for (int off = 1; off < 16; off <<= 1)
    #pragma unroll
    for (int i = 0; i < 4; ++i) {
      sv[i]  += __shfl_xor(sv[i], off);
      ssv[i] += __shfl_xor(ssv[i], off);
    }
  #pragma unroll
  for (int nt = 0; nt < 8; ++nt) {
    float gg = bfu(g[nt * 16 + lr]);
    float bb = bfu(be[nt * 16 + lr]);
    #pragma unroll
    for (int i = 0; i < 4; ++i) {
      float mean = sv[i] * (1.f / 128.f);
      float iv = rsqrtf(fmaxf(ssv[i] * (1.f / 128.f) - mean * mean, 0.f) + EPS_);
      hbuf[(size_t)(r0 + lq * 4 + i) * 128 + nt * 16 + lr] =
          f2bf((acc2[nt][i] - mean) * iv * gg + bb);
    }
  }
}

// head: one wave per image
__global__ __launch_bounds__(64)
void k_head(const ushort_t* __restrict__ hbuf, const ushort_t* __restrict__ qr1_w,
            const ushort_t* __restrict__ qr1_b, const ushort_t* __restrict__ qr2_w,
            const ushort_t* __restrict__ qr2_b, const ushort_t* __restrict__ q_weights,
            const ushort_t* __restrict__ clf_w, const ushort_t* __restrict__ clf_b,
            const int* __restrict__ flag, void* __restrict__ out) {
  __shared__ float scr[32];
  const int lane = threadIdx.x, b = blockIdx.x;
  const bool f32m = (*flag != 0);
  const uint32* hrow0 = (const uint32*)(hbuf + (size_t)b * 65 * 128);
  {
    int j = lane & 31;
    const uint32* w = (const uint32*)qr1_w + j * 64;
    float acc = 0.f;
    #pragma unroll 4
    for (int k2 = 0; k2 < 64; ++k2) {
      float ha, hb, wa, wb;
      bf2(hrow0[k2], ha, hb); bf2(w[k2], wa, wb);
      acc += ha * wa + hb * wb;
    }
    if (lane < 32) scr[lane] = fmaxf(acc + bfu(qr1_b[j]), 0.f);
  }
  __syncthreads();
  if (lane < 10) {
    float qo[4]; float cp = 1.f;
    #pragma unroll
    for (int j2 = 0; j2 < 4; ++j2) {
      float acc = 0.f;
      #pragma unroll
      for (int k = 0; k < 32; ++k) acc += scr[k] * bfu(qr2_w[j2 * 32 + k]);
      float qin = tanhf(acc + bfu(qr2_b[j2]));
      cp *= cosf(qin) * cosf(bfu(q_weights[j2]));
      qo[j2] = cp;
    }
    const uint32* cw = (const uint32*)clf_w + lane * 66;
    float acc = 0.f;
    #pragma unroll 4
    for (int k2 = 0; k2 < 64; ++k2) {
      float ha, hb, wa, wb;
      bf2(hrow0[k2], ha, hb); bf2(cw[k2], wa, wb);
      acc += ha * wa + hb * wb;
    }
    #pragma unroll
    for (int d = 0; d < 4; ++d) acc += qo[d] * bfu(clf_w[lane * 132 + 128 + d]);
    acc += bfu(clf_b[lane]);
    if (f32m) ((float*)out)[b * 10 + lane] = acc;
    else      ((ushort_t*)out)[b * 10 + lane] = f2bf(acc);
  }
}

// ================= fallback monolith (R10, known-pass 874us) =================
#define HS    136
#define KOF   0
#define VOF   9248
#define SLOF  18464
#define BIGN  29344

__global__ __launch_bounds__(320, 2)
void vit_mono(const ushort_t* __restrict__ x, const ushort_t* __restrict__ patch_w,
              const ushort_t* __restrict__ patch_b, const ushort_t* __restrict__ cls_token,
              const ushort_t* __restrict__ pos_embed, const ushort_t* __restrict__ qkv_w,
              const ushort_t* __restrict__ qkv_b, const ushort_t* __restrict__ out_w,
              const ushort_t* __restrict__ out_b, const ushort_t* __restrict__ ln1_s,
              const ushort_t* __restrict__ ln1_b, const ushort_t* __restrict__ ln2_s,
              const ushort_t* __restrict__ ln2_b, const ushort_t* __restrict__ ff1_w,
              const ushort_t* __restrict__ ff1_b, const ushort_t* __restrict__ ff2_w,
              const ushort_t* __restrict__ ff2_b, const ushort_t* __restrict__ qr1_w,
              const ushort_t* __restrict__ qr1_b, const ushort_t* __restrict__ qr2_w,
              const ushort_t* __restrict__ qr2_b, const ushort_t* __restrict__ q_weights,
              const ushort_t* __restrict__ clf_w, const ushort_t* __restrict__ clf_b,
              const int* __restrict__ flag, void* __restrict__ out)
{
  __shared__ __align__(16) ushort_t h_s[80 * HS];
  __shared__ __align__(16) ushort_t big[BIGN];
  const int tid = threadIdx.x, wid = tid >> 6, lane = tid & 63;
  const int lr = lane & 15, lq = lane >> 4;
  const int b = blockIdx.x;
  const bool f32m = (*flag != 0);
  const int m0 = wid * 16;
  uint32* bx = (uint32*)big;
  if (f32m) {
    const float* xf = (const float*)x + (size_t)b * 3072;
    for (int i = tid; i < 1536; i += 320) {
      uint32 lo = f2bf(xf[2 * i]);
      uint32 hi = f2bf(xf[2 * i + 1]);
      bx[i] = lo | (hi << 16);
    }
  } else {
    const uint32* xb = (const uint32*)x + (size_t)b * 1536;
    for (int i = tid; i < 1536; i += 320) bx[i] = xb[i];
  }
  { const uint32* pw = (const uint32*)patch_w;
    for (int i = tid; i < 3072; i += 320) bx[1536 + i] = pw[i]; }
  __syncthreads();
  #pragma unroll 1
  for (int idx = tid; idx < 8192; idx += 320) {
    int p = idx >> 7, d = idx & 127;
    int pi = p >> 3, pj = p & 7;
    float acc = 0.f;
    #pragma unroll
    for (int c = 0; c < 3; ++c)
      #pragma unroll
      for (int py = 0; py < 4; ++py) {
        const uint32* xr = bx + ((c * 1024 + (pi * 4 + py) * 32 + pj * 4) >> 1);
        const uint32* wr = bx + 1536 + ((d * 48 + c * 16 + py * 4) >> 1);
        #pragma unroll
        for (int q2 = 0; q2 < 2; ++q2) {
          float xa, xb2, wa, wb;
          bf2(xr[q2], xa, xb2); bf2(wr[q2], wa, wb);
          acc += xa * wa + xb2 * wb;
        }
      }
    acc += bfu(patch_b[d]) + bfu(pos_embed[(1 + p) * 128 + d]);
    h_s[(1 + p) * HS + d] = f2bf(acc);
  }
  if (tid < 128) h_s[tid] = f2bf(bfu(cls_token[tid]) + bfu(pos_embed[tid]));
  for (int i = tid; i < 15 * HS; i += 320) h_s[65 * HS + i] = 0;
  #pragma unroll 1
  for (int il = 0; il < 4; ++il) {
    __syncthreads();
    const ushort_t* Wqkv = qkv_w + (size_t)il * 384 * 128;
    const ushort_t* Bqkv = qkv_b + il * 384;
    const ushort_t* Wo   = out_w + (size_t)il * 128 * 128;
    ushort_t* bw = big + SLOF + wid * 2176;
    #pragma unroll 2
    for (int u = wid * 16; u < wid * 16 + 16; ++u) {
      int ty = u & 1, r = u >> 1;
      int mt = r >> 3, nt = r & 7;
      int km0 = mt * 16;
      int rb = (ty ? 256 : 128) + nt * 16;
      float bv = bfu(Bqkv[rb + lr]);
      f32x4 acc = {bv, bv, bv, bv};
      #pragma unroll
      for (int kc = 0; kc < 4; ++kc) {
        s16x8 a  = *(const s16x8*)&h_s[(km0 + lr) * HS + kc * 32 + lq * 8];
        s16x8 bb = *(const s16x8*)&Wqkv[(rb + lr) * 128 + kc * 32 + lq * 8];
        acc = MFMA16(a, bb, acc);
      }
      if (!ty) {
        #pragma unroll
        for (int i = 0; i < 4; ++i) {
          int row = km0 + lq * 4 + i;
          if (row < 68) big[KOF + row * 136 + nt * 16 + lr] = f2bf(acc[i]);
        }
      } else {
        int tk = km0 + lq * 4;
        if (tk < 68) {
          uint32 w0 = (uint32)f2bf(acc[0]) | ((uint32)f2bf(acc[1]) << 16);
          uint32 w1 = (uint32)f2bf(acc[2]) | ((uint32)f2bf(acc[3]) << 16);
          uint32* dst = (uint32*)&big[VOF + (nt * 16 + lr) * 72 + tk];
          dst[0] = w0; dst[1] = w1;
        }
      }
    }
    __syncthreads();
    {
      s16x8 ha[4];
      #pragma unroll
      for (int kc = 0; kc < 4; ++kc)
        ha[kc] = *(const s16x8*)&h_s[(m0 + lr) * HS + kc * 32 + lq * 8];
      f32x4 opA[8];
      #pragma unroll
      for (int nt = 0; nt < 8; ++nt) {
        float bv = bfu(out_b[il * 128 + nt * 16 + lr]);
        opA[nt] = (f32x4){bv, bv, bv, bv};
      }
      #pragma unroll 1
      for (int ih = 0; ih < 4; ++ih) {
        #pragma unroll
        for (int n2 = 0; n2 < 2; ++n2) {
          int rb = ih * 32 + n2 * 16;
          float bv = bfu(Bqkv[rb + lr]);
          f32x4 acc = {bv, bv, bv, bv};
          #pragma unroll
          for (int kc = 0; kc < 4; ++kc) {
            s16x8 bb = *(const s16x8*)&Wqkv[(rb + lr) * 128 + kc * 32 + lq * 8];
            acc = MFMA16(ha[kc], bb, acc);
          }
          #pragma unroll
          for (int i = 0; i < 4; ++i)
            bw[(lq * 4 + i) * 40 + n2 * 16 + lr] = f2bf(acc[i] * SCALE2_);
        }
        s16x8 aq = *(const s16x8*)&bw[lr * 40 + lq * 8];
        f32x4 S[5];
        #pragma unroll
        for (int jt = 0; jt < 5; ++jt) {
          s16x8 bb = *(const s16x8*)&big[KOF + (jt * 16 + lr) * 136 + ih * 32 + lq * 8];
          f32x4 z = {0.f, 0.f, 0.f, 0.f};
          S[jt] = MFMA16(aq, bb, z);
        }
        float mx[4] = {-1e30f, -1e30f, -1e30f, -1e30f};
        #pragma unroll
        for (int jt = 0; jt < 5; ++jt)
          #pragma unroll
          for (int i = 0; i < 4; ++i) {
            float sv = S[jt][i];
            if (jt == 4 && lr > 0) sv = -1e30f;
            S[jt][i] = sv;
            mx[i] = fmaxf(mx[i], sv);
          }
        #pragma unroll
        for (int off = 1; off < 16; off <<= 1)
          #pragma unroll
          for (int i = 0; i < 4; ++i) mx[i] = fmaxf(mx[i], __shfl_xor(mx[i], off));
        float sm[4] = {0.f, 0.f, 0.f, 0.f};
        #pragma unroll
        for (int jt = 0; jt < 5; ++jt)
          #pragma unroll
          for (int i = 0; i < 4; ++i) {
            float pv = exp2f(S[jt][i] - mx[i]);
            S[jt][i] = pv; sm[i] += pv;
          }
        #pragma unroll
        for (int off = 1; off < 16; off <<= 1)
          #pragma unroll
          for (int i = 0; i < 4; ++i) sm[i] += __shfl_xor(sm[i], off);
        float inv[4];
        #pragma unroll
        for (int i = 0; i < 4; ++i) inv[i] = 1.f / sm[i];
        #pragma unroll
        for (int i = 0; i < 4; ++i)
          #pragma unroll
          for (int jt = 0; jt < 4; ++jt)
            bw[(lq * 4 + i) * 72 + jt * 16 + lr] = f2bf(S[jt][i] * inv[i]);
        f32x4 ov[2];
        #pragma unroll
        for (int n2 = 0; n2 < 2; ++n2) {
          f32x4 acc = {0.f, 0.f, 0.f, 0.f};
          #pragma unroll
          for (int kc = 0; kc < 2; ++kc) {
            s16x8 a  = *(const s16x8*)&bw[lr * 72 + kc * 32 + lq * 8];
            s16x8 bb = *(const s16x8*)&big[VOF + (ih * 32 + n2 * 16 + lr) * 72 + kc * 32 + lq * 8];
            acc = MFMA16(a, bb, acc);
          }
          float v64 = bfu(big[VOF + (ih * 32 + n2 * 16 + lr) * 72 + 64]);
          #pragma unroll
          for (int i = 0; i < 4; ++i) {
            float p64 = __shfl(S[4][i], lane & 48) * inv[i];
            acc[i] += p64 * v64;
          }
          ov[n2] = acc;
        }
        #pragma unroll
        for (int n2 = 0; n2 < 2; ++n2)
          #pragma unroll
          for (int i = 0; i < 4; ++i)
            bw[(lq * 4 + i) * 40 + n2 * 16 + lr] = f2bf(ov[n2][i]);
        s16x8 ao = *(const s16x8*)&bw[lr * 40 + lq * 8];
        #pragma unroll
        for (int nt = 0; nt < 8; ++nt) {
          s16x8 bb = *(const s16x8*)&Wo[(nt * 16 + lr) * 128 + ih * 32 + lq * 8];
          opA[nt] = MFMA16(ao, bb, opA[nt]);
        }
      }
      float sv[4] = {0, 0, 0, 0}, ssv[4] = {0, 0, 0, 0};
      #pragma unroll
      for (int nt = 0; nt < 8; ++nt)
        #pragma unroll
        for (int i = 0; i < 4; ++i) {
          float r = opA[nt][i] + bfu(h_s[(m0 + lq * 4 + i) * HS + nt * 16 + lr]);
          opA[nt][i] = r; sv[i] += r; ssv[i] += r * r;
        }
      #pragma unroll
      for (int off = 1; off < 16; off <<= 1)
        #pragma unroll
        for (int i = 0; i < 4; ++i) {
          sv[i]  += __shfl_xor(sv[i], off);
          ssv[i] += __shfl_xor(ssv[i], off);
        }
      float mean[4], inv2[4];
      #pragma unroll
      for (int i = 0; i < 4; ++i) {
        mean[i] = sv[i] * (1.f / 128.f);
        inv2[i] = rsqrtf(fmaxf(ssv[i] * (1.f / 128.f) - mean[i] * mean[i], 0.f) + EPS_);
      }
      #pragma unroll
      for (int nt = 0; nt < 8; ++nt) {
        float g = bfu(ln1_s[il * 128 + nt * 16 + lr]);
        float be = bfu(ln1_b[il * 128 + nt * 16 + lr]);
        #pragma unroll
        for (int i = 0; i < 4; ++i)
          h_s[(m0 + lq * 4 + i) * HS + nt * 16 + lr] =
              f2bf((opA[nt][i] - mean[i]) * inv2[i] * g + be);
      }
      const ushort_t* W1 = ff1_w + (size_t)il * 256 * 128;
      const ushort_t* W2 = ff2_w + (size_t)il * 128 * 256;
      s16x8 hf[4];
      #pragma unroll
      for (int kc = 0; kc < 4; ++kc)
        hf[kc] = *(const s16x8*)&h_s[(m0 + lr) * HS + kc * 32 + lq * 8];
      f32x4 acc2[8];
      #pragma unroll
      for (int nt = 0; nt < 8; ++nt) {
        float bv = bfu(ff2_b[il * 128 + nt * 16 + lr]);
        acc2[nt] = (f32x4){bv, bv, bv, bv};
      }
      #pragma unroll 1
      for (int half = 0; half < 2; ++half) {
        #pragma unroll 2
        for (int n8 = 0; n8 < 8; ++n8) {
          int ng = half * 8 + n8;
          float bv = bfu(ff1_b[il * 256 + ng * 16 + lr]);
          f32x4 acc = {bv, bv, bv, bv};
          #pragma unroll
          for (int kc = 0; kc < 4; ++kc) {
            s16x8 bb = *(const s16x8*)&W1[(ng * 16 + lr) * 128 + kc * 32 + lq * 8];
            acc = MFMA16(hf[kc], bb, acc);
          }
          #pragma unroll
          for (int i = 0; i < 4; ++i)
            bw[(lq * 4 + i) * 136 + n8 * 16 + lr] = f2bf(fmaxf(acc[i], 0.f));
        }
        #pragma unroll
        for (int kc = 0; kc < 4; ++kc) {
          s16x8 a2 = *(const s16x8*)&bw[lr * 136 + kc * 32 + lq * 8];
          #pragma unroll
          for (int nt = 0; nt < 8; ++nt) {
            s16x8 bb = *(const s16x8*)&W2[(nt * 16 + lr) * 256 + half * 128 + kc * 32 + lq * 8];
            acc2[nt] = MFMA16(a2, bb, acc2[nt]);
          }
        }
      }
      float s2[4] = {0, 0, 0, 0}, ss2[4] = {0, 0, 0, 0};
      #pragma unroll
      for (int nt = 0; nt < 8; ++nt)
        #pragma unroll
        for (int i = 0; i < 4; ++i) {
          float r = acc2[nt][i] + bfu(h_s[(m0 + lq * 4 + i) * HS + nt * 16 + lr]);
          acc2[nt][i] = r; s2[i] += r; ss2[i] += r * r;
        }
      #pragma unroll
      for (int off = 1; off < 16; off <<= 1)
        #pragma unroll
        for (int i = 0; i < 4; ++i) {
          s2[i]  += __shfl_xor(s2[i], off);
          ss2[i] += __shfl_xor(ss2[i], off);
        }
      float mean2[4], invb[4];
      #pragma unroll
      for (int i = 0; i < 4; ++i) {
        mean2[i] = s2[i] * (1.f / 128.f);
        invb[i]  = rsqrtf(fmaxf(ss2[i] * (1.f / 128.f) - mean2[i] * mean2[i], 0.f) + EPS_);
      }
      #pragma unroll
      for (int nt = 0; nt < 8; ++nt) {
        float g = bfu(ln2_s[il * 128 + nt * 16 + lr]);
        float be = bfu(ln2_b[il * 128 + nt * 16 + lr]);
        #pragma unroll
        for (int i = 0; i < 4; ++i)
          h_s[(m0 + lq * 4 + i) * HS + nt * 16 + lr] =
              f2bf((acc2[nt][i] - mean2[i]) * invb[i] * g + be);
      }
    }
  }
  __syncthreads();
  float* scr = (float*)big;
  {
    int j = tid & 31;
    const uint32* hrow0 = (const uint32*)h_s;
    const uint32* w = (const uint32*)qr1_w + j * 64;
    float acc = 0.f;
    #pragma unroll 4
    for (int k2 = 0; k2 < 64; ++k2) {
      float ha, hb, wa, wb;
      bf2(hrow0[k2], ha, hb); bf2(w[k2], wa, wb);
      acc += ha * wa + hb * wb;
    }
    float u = fmaxf(acc + bfu(qr1_b[j]), 0.f);
    if (tid < 32) scr[tid] = u;
  }
  __syncthreads();
  if (tid < 10) {
    float qo[4]; float cp = 1.f;
    #pragma unroll
    for (int j2 = 0; j2 < 4; ++j2) {
      float acc = 0.f;
      #pragma unroll
      for (int k = 0; k < 32; ++k) acc += scr[k] * bfu(qr2_w[j2 * 32 + k]);
      float qin = tanhf(acc + bfu(qr2_b[j2]));
      cp *= cosf(qin) * cosf(bfu(q_weights[j2]));
      qo[j2] = cp;
    }
    const uint32* hrow0 = (const uint32*)h_s;
    const uint32* cw = (const uint32*)clf_w + tid * 66;
    float acc = 0.f;
    #pragma unroll 4
    for (int k2 = 0; k2 < 64; ++k2) {
      float ha, hb, wa, wb;
      bf2(hrow0[k2], ha, hb); bf2(cw[k2], wa, wb);
      acc += ha * wa + hb * wb;
    }
    #pragma unroll
    for (int d = 0; d < 4; ++d) acc += qo[d] * bfu(clf_w[tid * 132 + 128 + d]);
    acc += bfu(clf_b[tid]);
    if (f32m) ((float*)out)[b * 10 + tid] = acc;
    else      ((ushort_t*)out)[b * 10 + tid] = f2bf(acc);
  }
}

extern "C" void kernel_launch(void* const* d_in, const int* in_sizes, int n_in,
                              void* d_out, int out_size, void* d_ws, size_t ws_size,
                              hipStream_t stream) {
  WPack p;
  unsigned cur = 0;
  for (int i = 0; i < 23; ++i) {
    p.src[i] = d_in[i + 1];
    p.off[i] = cur;
    p.n[i]   = (unsigned)in_sizes[i + 1];
    cur += (p.n[i] + 7u) & ~7u;
  }
  ushort_t* wsb = (ushort_t*)d_ws;
  const ushort_t* x = (const ushort_t*)d_in[0];
  size_t wb = (size_t)cur * 2;
  size_t fb = (wb + 3) & ~(size_t)3;
  int* flagp = (int*)((char*)d_ws + fb);

  canon<<<dim3(128), dim3(256), 0, stream>>>(p, x, wsb, flagp);

  int B = out_size / 10;
  size_t HB = (size_t)B * 65 * 128 * 2;
  size_t QB = (size_t)B * 4 * 80 * 32 * 2;
  size_t hb = (fb + 4 + 255) & ~(size_t)255;
  size_t qo = hb + HB, ko = qo + QB, vo = ko + QB, oo = vo + QB;
  size_t need = oo + HB;
  size_t FBYT = (size_t)B * 65 * 256 * 2;   // fbuf aliases q/k/vT region
  bool pipe = (ws_size >= need) && (B % 64 == 0) && (FBYT <= 3 * QB);

  #define WP(i) (wsb + p.off[i])
  if (pipe) {
    ushort_t* hbuf = (ushort_t*)((char*)d_ws + hb);
    ushort_t* qb   = (ushort_t*)((char*)d_ws + qo);
    ushort_t* kb   = (ushort_t*)((char*)d_ws + ko);
    ushort_t* vtb  = (ushort_t*)((char*)d_ws + vo);
    ushort_t* obuf = (ushort_t*)((char*)d_ws + oo);
    ushort_t* fbuf = qb;   // alias: qkv dead before ff1 writes
    int MT = (B * 65) / 64;

    k_patch<<<dim3(B), dim3(256), 0, stream>>>(x, WP(0), WP(1), WP(2), WP(3), flagp, hbuf);
    for (int il = 0; il < 4; ++il) {
      k_qkv<<<dim3(MT, 6), dim3(256), 0, stream>>>(
          hbuf, WP(4) + (size_t)il * 49152, WP(5) + il * 384, qb, kb, vtb);
      k_attn<<<dim3(B * 4), dim3(64), 0, stream>>>(qb, kb, vtb, obuf);
      k_out_ln<<<dim3(MT), dim3(256), 0, stream>>>(
          obuf, WP(6) + (size_t)il * 16384, WP(7) + il * 128,
          WP(8) + il * 128, WP(9) + il * 128, hbuf);
      k_ff1<<<dim3(MT, 4), dim3(256), 0, stream>>>(
          hbuf, WP(12) + (size_t)il * 32768, WP(13) + il * 256, fbuf);
      k_ff2_ln<<<dim3(MT), dim3(256), 0, stream>>>(
          fbuf, WP(14) + (size_t)il * 32768, WP(15) + il * 128,
          WP(10) + il * 128, WP(11) + il * 128, hbuf);
    }
    k_head<<<dim3(B), dim3(64), 0, stream>>>(
        hbuf, WP(16), WP(17), WP(18), WP(19), WP(20), WP(21), WP(22), flagp, d_out);
  } else {
    vit_mono<<<dim3(B), dim3(320), 0, stream>>>(
        x, WP(0), WP(1), WP(2), WP(3), WP(4), WP(5), WP(6), WP(7), WP(8), WP(9),
        WP(10), WP(11), WP(12), WP(13), WP(14), WP(15), WP(16), WP(17), WP(18),
        WP(19), WP(20), WP(21), WP(22), flagp, d_out);
  }
  #undef WP
}